// Round 3
// baseline (205.729 us; speedup 1.0000x reference)
//
#include <hip/hip_runtime.h>

#define NBLOCKS 2048
#define NTHREADS 256

__device__ __forceinline__ float wave_reduce_sum(float v) {
#pragma unroll
    for (int off = 32; off > 0; off >>= 1)
        v += __shfl_down(v, off, 64);
    return v;
}

// quat2mat per reference (row-major 3x3)
__device__ __forceinline__ void quat2mat(float q0, float q1, float q2, float q3,
                                         float m[9]) {
    float q00 = q0 * q0, q11 = q1 * q1, q22 = q2 * q2, q33 = q3 * q3;
    m[0] = q00 + q11 - q22 - q33;
    m[1] = 2.0f * (q1 * q2 - q0 * q3);
    m[2] = 2.0f * (q1 * q3 + q0 * q2);
    m[3] = 2.0f * (q1 * q2 + q0 * q3);
    m[4] = q00 - q11 + q22 - q33;
    m[5] = 2.0f * (q2 * q3 - q0 * q1);
    m[6] = 2.0f * (q1 * q3 - q0 * q2);
    m[7] = 2.0f * (q2 * q3 + q0 * q1);
    m[8] = q00 - q11 - q22 + q33;
}

// Per-block 3-way block reduction -> dst[0..2]
__device__ __forceinline__ void block_reduce3(float c, float d, float r,
                                              float* dst) {
    c = wave_reduce_sum(c);
    d = wave_reduce_sum(d);
    r = wave_reduce_sum(r);
    __shared__ float s_c[NTHREADS / 64], s_d[NTHREADS / 64], s_r[NTHREADS / 64];
    const int lane = threadIdx.x & 63;
    const int wid = threadIdx.x >> 6;
    if (lane == 0) {
        s_c[wid] = c;
        s_d[wid] = d;
        s_r[wid] = r;
    }
    __syncthreads();
    if (threadIdx.x == 0) {
        float tc = 0.0f, td = 0.0f, tr = 0.0f;
#pragma unroll
        for (int w = 0; w < NTHREADS / 64; ++w) {
            tc += s_c[w];
            td += s_d[w];
            tr += s_r[w];
        }
        dst[0] = tc;
        dst[1] = td;
        dst[2] = tr;
    }
}

__device__ __forceinline__ float wsq(float4 c, float4 g, float4 w) {
    float d0 = c.x - g.x, d1 = c.y - g.y, d2 = c.z - g.z, d3 = c.w - g.w;
    return w.x * d0 * d0 + w.y * d1 * d1 + w.z * d2 * d2 + w.w * d3 * d3;
}

__global__ __launch_bounds__(NTHREADS) void hpnet_partial_kernel(
    const float* __restrict__ conf, const float* __restrict__ conf_gt,
    const float* __restrict__ weight, const float* __restrict__ dr,
    const float* __restrict__ ann, const int* __restrict__ flags,
    float* __restrict__ part,  // (NBLOCKS, 3)
    long long n_conf, int N) {
    const long long gid = (long long)blockIdx.x * blockDim.x + threadIdx.x;
    const long long gstride = (long long)gridDim.x * blockDim.x;

    // ---- Part 1: confidence loss ------------------------------------------
    const float4* __restrict__ c4 = (const float4*)conf;
    const float4* __restrict__ g4 = (const float4*)conf_gt;
    const float4* __restrict__ w4 = (const float4*)weight;
    const long long n4 = n_conf >> 2;  // 4194304

    // unroll x4, 12 outstanding dwordx4 loads per wave, 4 indep accumulators
    float acc0 = 0.0f, acc1 = 0.0f, acc2 = 0.0f, acc3 = 0.0f;
    long long i = gid;
    for (; i + 3 * gstride < n4; i += 4 * gstride) {
        float4 ca = c4[i];
        float4 cb = c4[i + gstride];
        float4 cc = c4[i + 2 * gstride];
        float4 cd = c4[i + 3 * gstride];
        float4 ga = g4[i];
        float4 gb = g4[i + gstride];
        float4 gc = g4[i + 2 * gstride];
        float4 gd = g4[i + 3 * gstride];
        float4 wa = w4[i];
        float4 wb = w4[i + gstride];
        float4 wc = w4[i + 2 * gstride];
        float4 wd = w4[i + 3 * gstride];
        acc0 += wsq(ca, ga, wa);
        acc1 += wsq(cb, gb, wb);
        acc2 += wsq(cc, gc, wc);
        acc3 += wsq(cd, gd, wd);
    }
    for (; i < n4; i += gstride) acc0 += wsq(c4[i], g4[i], w4[i]);
    float acc_c = (acc0 + acc1) + (acc2 + acc3);

    // ---- Part 2 + 3: depth & rotation losses (tiny) -----------------------
    float acc_d = 0.0f;
    float acc_r = 0.0f;
    for (long long n = gid; n < N; n += gstride) {
        float m = flags[n] ? 1.0f : 0.0f;

        float de = dr[n * 5 + 0] - ann[n * 5 + 0];
        acc_d += m * de * de;

        float mp[9];
        quat2mat(ann[n * 5 + 1], ann[n * 5 + 2], ann[n * 5 + 3],
                 ann[n * 5 + 4], mp);

        float p0 = dr[n * 5 + 1], p1 = dr[n * 5 + 2], p2 = dr[n * 5 + 3],
              p3 = dr[n * 5 + 4];
        float inv = 1.0f / sqrtf(p0 * p0 + p1 * p1 + p2 * p2 + p3 * p3);
        float mg[9];
        quat2mat(p0 * inv, p1 * inv, p2 * inv, p3 * inv, mg);

        // RY = diag(-1,1,-1): m_pred @ RY negates cols 0 and 2
        float s1 = 0.0f, s2 = 0.0f;
#pragma unroll
        for (int r = 0; r < 3; ++r) {
            float a0 = mg[r * 3 + 0], a1 = mg[r * 3 + 1], a2 = mg[r * 3 + 2];
            float b0 = mp[r * 3 + 0], b1 = mp[r * 3 + 1], b2 = mp[r * 3 + 2];
            float e0 = a0 - b0, e1 = a1 - b1, e2 = a2 - b2;
            s1 += e0 * e0 + e1 * e1 + e2 * e2;
            float f0 = a0 + b0, f2 = a2 + b2;
            s2 += f0 * f0 + e1 * e1 + f2 * f2;
        }
        acc_r += m * fminf(sqrtf(s1), sqrtf(s2));
    }

    block_reduce3(acc_c, acc_d, acc_r, &part[3 * blockIdx.x]);
}

__global__ __launch_bounds__(NTHREADS) void hpnet_final_kernel(
    const float* __restrict__ part,  // (NBLOCKS, 3)
    float* __restrict__ out) {
    float tc = 0.0f, td = 0.0f, tr = 0.0f;
    for (int i = threadIdx.x; i < NBLOCKS; i += NTHREADS) {
        tc += part[3 * i + 0];
        td += part[3 * i + 1];
        tr += part[3 * i + 2];
    }
    __shared__ float dst[3];
    block_reduce3(tc, td, tr, dst);
    __syncthreads();
    if (threadIdx.x == 0) {
        out[0] = dst[0] * (1.0f / (256.0f * 256.0f));
        out[1] = dst[1] * (1.0f / 8192.0f);
        out[2] = dst[2] * (1.0f / 8192.0f);
    }
}

extern "C" void kernel_launch(void* const* d_in, const int* in_sizes, int n_in,
                              void* d_out, int out_size, void* d_ws,
                              size_t ws_size, hipStream_t stream) {
    const float* conf    = (const float*)d_in[0];
    const float* conf_gt = (const float*)d_in[1];
    const float* weight  = (const float*)d_in[2];
    const float* dr      = (const float*)d_in[3];
    const float* ann     = (const float*)d_in[4];
    const int*   flags   = (const int*)d_in[5];
    float* out = (float*)d_out;
    float* part = (float*)d_ws;  // NBLOCKS*3 floats

    const long long n_conf = (long long)in_sizes[0];  // 16777216
    const int N = in_sizes[5];                        // 8192

    hpnet_partial_kernel<<<NBLOCKS, NTHREADS, 0, stream>>>(
        conf, conf_gt, weight, dr, ann, flags, part, n_conf, N);
    hpnet_final_kernel<<<1, NTHREADS, 0, stream>>>(part, out);
}